// Round 16
// baseline (97.308 us; speedup 1.0000x reference)
//
#include <hip/hip_runtime.h>

#define B_ 8
#define C_ 256
#define N_ 4096
#define CK 32
#define CG 128
#define M_ 1024

typedef __attribute__((ext_vector_type(8))) short bf16x8;
typedef __attribute__((ext_vector_type(4))) float f32x4;

__device__ __forceinline__ short f2bf(float f) {
  union { float f; unsigned u; } v; v.f = f;
  unsigned r = (v.u + 0x7FFF + ((v.u >> 16) & 1)) >> 16;  // RNE
  return (short)r;
}
__device__ __forceinline__ int cvtpk(float lo, float hi) {
  int r;
  asm("v_cvt_pk_bf16_f32 %0, %1, %2" : "=v"(r) : "v"(lo), "v"(hi));
  return r;
}
__device__ __forceinline__ float vexp2(float x) {  // 2^x
  float r;
  asm("v_exp_f32 %0, %1" : "=v"(r) : "v"(x));
  return r;
}
__device__ __forceinline__ bf16x8 asbf(int4 v) {
  union { int4 i; bf16x8 b; } u; u.i = v; return u.b;
}

// ---------------- fused projection: theta (unpooled) + phi/g (2x2 maxpooled)
// w_theta rows are pre-scaled by log2(e) so attention logits come out in the
// log2 domain (softmax uses raw v_exp_f32 = 2^x, no per-element multiply).
// g is written with the J<->h m-bit permutation so attention's PV B-operand
// (P) is register-local.
__global__ __launch_bounds__(512) void proj_kernel(const float* __restrict__ x,
                                                   const float* __restrict__ wt,
                                                   const float* __restrict__ wp,
                                                   const float* __restrict__ wg,
                                                   short* __restrict__ theta_t,
                                                   short* __restrict__ phi_t,
                                                   short* __restrict__ g_bf) {
  __shared__ __align__(16) short w_s[192 * 256];  // 96 KB, 16B-group swizzle g^(o&7)
  __shared__ __align__(16) short x_s[64 * 256];   // 32 KB, 16B-group swizzle g^(nl&7)
  int tid = threadIdx.x;
  int bx = blockIdx.x, b = blockIdx.y;
  int t = bx >> 1, half = bx & 1;

#pragma unroll
  for (int rep = 0; rep < 12; ++rep) {
    int idx = rep * 512 + tid;
    int o = idx >> 5, gp = idx & 31;
    const float* src = (o < 32) ? (wt + o * 256)
                     : (o < 64) ? (wp + (o - 32) * 256)
                                : (wg + (o - 64) * 256);
    float sc = (o < 32) ? 1.44269504f : 1.f;  // log2(e) folded into theta
    float4 f0 = *(const float4*)(src + gp * 8);
    float4 f1 = *(const float4*)(src + gp * 8 + 4);
    int4 pk;
    pk.x = cvtpk(f0.x * sc, f0.y * sc); pk.y = cvtpk(f0.z * sc, f0.w * sc);
    pk.z = cvtpk(f1.x * sc, f1.y * sc); pk.w = cvtpk(f1.z * sc, f1.w * sc);
    *(int4*)&w_s[o * 256 + ((gp ^ (o & 7)) * 8)] = pk;
  }
  {
    int l = tid & 63, cq = tid >> 6;
    int xoff = l >> 1, dy = l & 1;
    int n = t * 128 + dy * 64 + half * 32 + xoff;
    const float* xb = x + (size_t)b * C_ * N_ + n;
#pragma unroll
    for (int rep = 0; rep < 2; ++rep) {
      int ch = cq + rep * 8;
      int c0 = ch * 16;
      float f[16];
#pragma unroll
      for (int i = 0; i < 16; ++i) f[i] = xb[(size_t)(c0 + i) * N_];
      int4 pa, pb;
      pa.x = cvtpk(f[0], f[1]);   pa.y = cvtpk(f[2], f[3]);
      pa.z = cvtpk(f[4], f[5]);   pa.w = cvtpk(f[6], f[7]);
      pb.x = cvtpk(f[8], f[9]);   pb.y = cvtpk(f[10], f[11]);
      pb.z = cvtpk(f[12], f[13]); pb.w = cvtpk(f[14], f[15]);
      *(int4*)&x_s[l * 256 + (((2 * ch) ^ (l & 7)) * 8)] = pa;
      *(int4*)&x_s[l * 256 + (((2 * ch + 1) ^ (l & 7)) * 8)] = pb;
    }
  }
  __syncthreads();

  int lane = tid & 63, w = tid >> 6;
  int h = lane >> 4, q = lane & 15;
  int ns = w & 3, ow = w >> 2;
  f32x4 acc[6];
#pragma unroll
  for (int j = 0; j < 6; ++j) acc[j] = (f32x4){0.f, 0.f, 0.f, 0.f};

  int nl = 16 * ns + q;
#pragma unroll
  for (int ks = 0; ks < 8; ++ks) {
    bf16x8 bfr = *(const bf16x8*)&x_s[nl * 256 + (((4 * ks + h) ^ (nl & 7)) * 8)];
#pragma unroll
    for (int j = 0; j < 6; ++j) {
      int o = 16 * (6 * ow + j) + q;
      bf16x8 afr = *(const bf16x8*)&w_s[o * 256 + (((4 * ks + h) ^ (o & 7)) * 8)];
      acc[j] = __builtin_amdgcn_mfma_f32_16x16x32_bf16(afr, bfr, acc[j], 0, 0, 0);
    }
  }

  int xoff = nl >> 1, dy = nl & 1;
  int n = t * 128 + dy * 64 + half * 32 + xoff;
  int m = t * 32 + half * 16 + (nl >> 2);
  // permuted g position: swap the J (bit4) and h (bits3:2) fields of m
  int mp = (m & ~31) | (((m >> 2) & 3) << 3) | (((m >> 4) & 1) << 2) | (m & 3);
#pragma unroll
  for (int j = 0; j < 6; ++j) {
    int ot = 6 * ow + j;
    if (ot < 2) {  // theta, unpooled (log2e-scaled)
      int2 pp;
      pp.x = cvtpk(acc[j][0], acc[j][1]);
      pp.y = cvtpk(acc[j][2], acc[j][3]);
      *(int2*)&theta_t[((size_t)b * N_ + n) * CK + ot * 16 + 4 * h] = pp;
    } else {  // pooled
      float v[4];
#pragma unroll
      for (int r = 0; r < 4; ++r) {
        float vv = acc[j][r];
        vv = fmaxf(vv, __shfl_xor(vv, 1));
        vv = fmaxf(vv, __shfl_xor(vv, 2));
        v[r] = vv;
      }
      if ((nl & 3) == 0) {
        if (ot < 4) {  // phi (natural m order)
          int2 pp;
          pp.x = cvtpk(v[0], v[1]);
          pp.y = cvtpk(v[2], v[3]);
          *(int2*)&phi_t[((size_t)b * M_ + m) * CK + (ot - 2) * 16 + 4 * h] = pp;
        } else {  // g (permuted m position)
#pragma unroll
          for (int r = 0; r < 4; ++r) {
            int oc = (ot - 4) * 16 + 4 * h + r;
            g_bf[((size_t)b * CG + oc) * M_ + mp] = f2bf(v[r]);
          }
        }
      }
    }
  }
}

// ---------------- fused flash-attention + out-projection + residual
// NO LDS, NO BARRIERS in the main loop: V (g) is read directly from L1/L2
// (256 KB/batch, XCD-local via b-swizzle — L2-resident; m169 lesson: don't
// LDS-stage cache-fit data). V fragment loads issue at iter top and are
// consumed by PV after QK+exp (~400 cyc) — L2 latency hidden in-wave. phi
// prefetched one tile ahead in registers. P register-local (permuted g).
// Softmax = raw v_exp_f32 (theta pre-scaled by log2e). 512 blocks x 256 thr
// (4 independent waves each), 2 blocks/CU, 8 waves/CU.
__global__ __launch_bounds__(256, 2) void attn_out_kernel(const short* __restrict__ theta_t,
                                                          const short* __restrict__ phi_t,
                                                          const short* __restrict__ g_bf,
                                                          const float* __restrict__ wo,
                                                          const float* __restrict__ x,
                                                          const float* __restrict__ gamma,
                                                          float* __restrict__ out) {
  __shared__ __align__(16) short lds[25088];  // 50,176 B, epilogue only

  int tid = threadIdx.x;
  int lane = tid & 63, w = tid >> 6;
  int h = lane >> 4, q = lane & 15;
  int bid = blockIdx.x;
  int b = bid & 7, n0 = (bid >> 3) * 64;  // same-b blocks share an XCD L2
  int n = n0 + 16 * w + q;
  float gm = gamma[0];

  bf16x8 qfrag = *(const bf16x8*)&theta_t[((size_t)b * N_ + n) * CK + 8 * h];

  f32x4 Oacc[8];
#pragma unroll
  for (int ct = 0; ct < 8; ++ct) Oacc[ct] = (f32x4){0.f, 0.f, 0.f, 0.f};
  float S = 0.f;
  const f32x4 zero4 = {0.f, 0.f, 0.f, 0.f};

  const short* phi_b = phi_t + (size_t)b * M_ * CK;
  const short* g_b = g_bf + (size_t)b * CG * M_;

  int4 pcur[4];
#pragma unroll
  for (int mt = 0; mt < 4; ++mt)
    pcur[mt] = *(const int4*)&phi_b[(16 * mt + q) * CK + 8 * h];

  for (int it = 0; it < 16; ++it) {
    int m0 = it * 64;
    // V fragments for THIS tile: 16 coalesced 16B/lane loads from L1/L2
    int4 vf[16];
#pragma unroll
    for (int ct = 0; ct < 8; ++ct)
#pragma unroll
      for (int kp = 0; kp < 2; ++kp)
        vf[2 * ct + kp] =
            *(const int4*)&g_b[(size_t)(16 * ct + q) * M_ + m0 + 32 * kp + 8 * h];
    // phi prefetch for NEXT tile
    int4 pnxt[4];
    if (it < 15) {
#pragma unroll
      for (int mt = 0; mt < 4; ++mt)
        pnxt[mt] = *(const int4*)&phi_b[(m0 + 64 + 16 * mt + q) * CK + 8 * h];
    }

    // QK^T from registers (logits already in log2 domain)
    f32x4 pt[4];
#pragma unroll
    for (int mt = 0; mt < 4; ++mt)
      pt[mt] = __builtin_amdgcn_mfma_f32_16x16x32_bf16(asbf(pcur[mt]), qfrag, zero4, 0, 0, 0);

    // static softmax numerator: P = 2^logit; P stays in registers
    int2 pk[4];
#pragma unroll
    for (int mt = 0; mt < 4; ++mt) {
      float e0 = vexp2(pt[mt][0]);
      float e1 = vexp2(pt[mt][1]);
      float e2 = vexp2(pt[mt][2]);
      float e3 = vexp2(pt[mt][3]);
      S += (e0 + e1) + (e2 + e3);
      pk[mt].x = cvtpk(e0, e1);
      pk[mt].y = cvtpk(e2, e3);
    }

    // PV: O^T[all 128 c][own 16 n]; A = vf regs (waits on loads), B = pk regs
    __builtin_amdgcn_s_setprio(1);
#pragma unroll
    for (int kp = 0; kp < 2; ++kp) {
      int4 pfi;
      pfi.x = pk[2 * kp].x;     pfi.y = pk[2 * kp].y;
      pfi.z = pk[2 * kp + 1].x; pfi.w = pk[2 * kp + 1].y;
      bf16x8 pf = asbf(pfi);
#pragma unroll
      for (int ct = 0; ct < 8; ++ct)
        Oacc[ct] = __builtin_amdgcn_mfma_f32_16x16x32_bf16(asbf(vf[2 * ct + kp]), pf,
                                                           Oacc[ct], 0, 0, 0);
    }
    __builtin_amdgcn_s_setprio(0);

    if (it < 15) {
#pragma unroll
      for (int mt = 0; mt < 4; ++mt) pcur[mt] = pnxt[mt];
    }
  }

  // cross-lane denominator reduce (once)
  S += __shfl_xor(S, 16);
  S += __shfl_xor(S, 32);

  // ---- epilogue: O -> LDS; w_o staged in two 128-row halves (r11-proven)
  short* ot_s = lds;           // 64 n x stride 136 = 8704 sh
  short* wo_s = lds + 8704;    // 128 o x 128 c = 16384 sh, swizzle g^(o&7)
  float rS = 1.f / S;
  int nloc = 16 * w + q;
#pragma unroll
  for (int ct = 0; ct < 8; ++ct) {
    int2 pp;
    pp.x = cvtpk(Oacc[ct][0] * rS, Oacc[ct][1] * rS);
    pp.y = cvtpk(Oacc[ct][2] * rS, Oacc[ct][3] * rS);
    *(int2*)&ot_s[nloc * 136 + 16 * ct + 4 * h] = pp;
  }

#pragma unroll
  for (int ho = 0; ho < 2; ++ho) {
    // stage w_o rows [128*ho, 128*ho+128) from f32
#pragma unroll
    for (int rep = 0; rep < 8; ++rep) {
      int idx = rep * 256 + tid;
      int ol = idx >> 4, gp = idx & 15;
      const float* src = wo + (size_t)(128 * ho + ol) * 128 + gp * 8;
      float4 f0 = *(const float4*)src;
      float4 f1 = *(const float4*)(src + 4);
      int4 pk2;
      pk2.x = cvtpk(f0.x, f0.y); pk2.y = cvtpk(f0.z, f0.w);
      pk2.z = cvtpk(f1.x, f1.y); pk2.w = cvtpk(f1.z, f1.w);
      *(int4*)&wo_s[ol * 128 + ((gp ^ (ol & 7)) * 8)] = pk2;
    }
    __syncthreads();

    // wave w: o-slice [32w, 32w+32), all 64 n
    f32x4 acc[2][4];
#pragma unroll
    for (int j = 0; j < 2; ++j)
#pragma unroll
      for (int nt = 0; nt < 4; ++nt) acc[j][nt] = (f32x4){0.f, 0.f, 0.f, 0.f};

#pragma unroll
    for (int ks = 0; ks < 4; ++ks) {
      bf16x8 bfr[4];
#pragma unroll
      for (int nt = 0; nt < 4; ++nt)
        bfr[nt] = *(const bf16x8*)&ot_s[(16 * nt + q) * 136 + 32 * ks + 8 * h];
#pragma unroll
      for (int j = 0; j < 2; ++j) {
        int ol = 32 * w + 16 * j + q;
        bf16x8 afr = *(const bf16x8*)&wo_s[ol * 128 + (((4 * ks + h) ^ (ol & 7)) * 8)];
#pragma unroll
        for (int nt = 0; nt < 4; ++nt)
          acc[j][nt] = __builtin_amdgcn_mfma_f32_16x16x32_bf16(afr, bfr[nt], acc[j][nt], 0, 0, 0);
      }
    }

#pragma unroll
    for (int j = 0; j < 2; ++j)
#pragma unroll
      for (int nt = 0; nt < 4; ++nt)
#pragma unroll
        for (int r = 0; r < 4; ++r) {
          int o = 128 * ho + 32 * w + 16 * j + 4 * h + r;
          int nn = n0 + 16 * nt + q;
          size_t idx = ((size_t)b * C_ + o) * N_ + nn;
          out[idx] = gm * acc[j][nt][r] + x[idx];
        }
    if (ho == 0) __syncthreads();  // wo_s reads done before restage
  }
}

extern "C" void kernel_launch(void* const* d_in, const int* in_sizes, int n_in,
                              void* d_out, int out_size, void* d_ws, size_t ws_size,
                              hipStream_t stream) {
  const float* x = (const float*)d_in[0];
  const float* wt = (const float*)d_in[1];
  const float* wp = (const float*)d_in[2];
  const float* wg = (const float*)d_in[3];
  const float* wo = (const float*)d_in[4];
  const float* gamma = (const float*)d_in[5];
  float* out = (float*)d_out;

  short* theta_t = (short*)d_ws;                       // 8*4096*32
  short* phi_t = theta_t + (size_t)B_ * N_ * CK;       // 8*1024*32
  short* g_bf = phi_t + (size_t)B_ * M_ * CK;          // 8*128*1024

  proj_kernel<<<dim3(64, 8), 512, 0, stream>>>(x, wt, wp, wg, theta_t, phi_t, g_bf);
  attn_out_kernel<<<dim3(512), 256, 0, stream>>>(theta_t, phi_t, g_bf, wo, x, gamma, out);
}

// Round 17
// 56.059 us; speedup vs baseline: 1.7358x; 1.7358x over previous
//
#include <hip/hip_runtime.h>

#define B_ 8
#define C_ 256
#define N_ 4096
#define CK 32
#define CG 128
#define M_ 1024

typedef __attribute__((ext_vector_type(8))) short bf16x8;
typedef __attribute__((ext_vector_type(4))) float f32x4;

__device__ __forceinline__ short f2bf(float f) {
  union { float f; unsigned u; } v; v.f = f;
  unsigned r = (v.u + 0x7FFF + ((v.u >> 16) & 1)) >> 16;  // RNE
  return (short)r;
}
__device__ __forceinline__ int cvtpk(float lo, float hi) {
  int r;
  asm("v_cvt_pk_bf16_f32 %0, %1, %2" : "=v"(r) : "v"(lo), "v"(hi));
  return r;
}
__device__ __forceinline__ bf16x8 asbf(int4 v) {
  union { int4 i; bf16x8 b; } u; u.i = v; return u.b;
}

// ---------------- fused projection: theta (unpooled) + phi/g (2x2 maxpooled)
// g is written with the J<->h m-bit permutation so attention's PV B-operand
// (P) is register-local.
__global__ __launch_bounds__(512) void proj_kernel(const float* __restrict__ x,
                                                   const float* __restrict__ wt,
                                                   const float* __restrict__ wp,
                                                   const float* __restrict__ wg,
                                                   short* __restrict__ theta_t,
                                                   short* __restrict__ phi_t,
                                                   short* __restrict__ g_bf) {
  __shared__ __align__(16) short w_s[192 * 256];  // 96 KB, 16B-group swizzle g^(o&7)
  __shared__ __align__(16) short x_s[64 * 256];   // 32 KB, 16B-group swizzle g^(nl&7)
  int tid = threadIdx.x;
  int bx = blockIdx.x, b = blockIdx.y;
  int t = bx >> 1, half = bx & 1;

#pragma unroll
  for (int rep = 0; rep < 12; ++rep) {
    int idx = rep * 512 + tid;
    int o = idx >> 5, gp = idx & 31;
    const float* src = (o < 32) ? (wt + o * 256)
                     : (o < 64) ? (wp + (o - 32) * 256)
                                : (wg + (o - 64) * 256);
    float4 f0 = *(const float4*)(src + gp * 8);
    float4 f1 = *(const float4*)(src + gp * 8 + 4);
    int4 pk;
    pk.x = cvtpk(f0.x, f0.y); pk.y = cvtpk(f0.z, f0.w);
    pk.z = cvtpk(f1.x, f1.y); pk.w = cvtpk(f1.z, f1.w);
    *(int4*)&w_s[o * 256 + ((gp ^ (o & 7)) * 8)] = pk;
  }
  {
    int l = tid & 63, cq = tid >> 6;
    int xoff = l >> 1, dy = l & 1;
    int n = t * 128 + dy * 64 + half * 32 + xoff;
    const float* xb = x + (size_t)b * C_ * N_ + n;
#pragma unroll
    for (int rep = 0; rep < 2; ++rep) {
      int ch = cq + rep * 8;
      int c0 = ch * 16;
      float f[16];
#pragma unroll
      for (int i = 0; i < 16; ++i) f[i] = xb[(size_t)(c0 + i) * N_];
      int4 pa, pb;
      pa.x = cvtpk(f[0], f[1]);   pa.y = cvtpk(f[2], f[3]);
      pa.z = cvtpk(f[4], f[5]);   pa.w = cvtpk(f[6], f[7]);
      pb.x = cvtpk(f[8], f[9]);   pb.y = cvtpk(f[10], f[11]);
      pb.z = cvtpk(f[12], f[13]); pb.w = cvtpk(f[14], f[15]);
      *(int4*)&x_s[l * 256 + (((2 * ch) ^ (l & 7)) * 8)] = pa;
      *(int4*)&x_s[l * 256 + (((2 * ch + 1) ^ (l & 7)) * 8)] = pb;
    }
  }
  __syncthreads();

  int lane = tid & 63, w = tid >> 6;
  int h = lane >> 4, q = lane & 15;
  int ns = w & 3, ow = w >> 2;
  f32x4 acc[6];
#pragma unroll
  for (int j = 0; j < 6; ++j) acc[j] = (f32x4){0.f, 0.f, 0.f, 0.f};

  int nl = 16 * ns + q;
#pragma unroll
  for (int ks = 0; ks < 8; ++ks) {
    bf16x8 bfr = *(const bf16x8*)&x_s[nl * 256 + (((4 * ks + h) ^ (nl & 7)) * 8)];
#pragma unroll
    for (int j = 0; j < 6; ++j) {
      int o = 16 * (6 * ow + j) + q;
      bf16x8 afr = *(const bf16x8*)&w_s[o * 256 + (((4 * ks + h) ^ (o & 7)) * 8)];
      acc[j] = __builtin_amdgcn_mfma_f32_16x16x32_bf16(afr, bfr, acc[j], 0, 0, 0);
    }
  }

  int xoff = nl >> 1, dy = nl & 1;
  int n = t * 128 + dy * 64 + half * 32 + xoff;
  int m = t * 32 + half * 16 + (nl >> 2);
  // permuted g position: swap the J (bit4) and h (bits3:2) fields of m
  int mp = (m & ~31) | (((m >> 2) & 3) << 3) | (((m >> 4) & 1) << 2) | (m & 3);
#pragma unroll
  for (int j = 0; j < 6; ++j) {
    int ot = 6 * ow + j;
    if (ot < 2) {  // theta, unpooled
      int2 pp;
      pp.x = cvtpk(acc[j][0], acc[j][1]);
      pp.y = cvtpk(acc[j][2], acc[j][3]);
      *(int2*)&theta_t[((size_t)b * N_ + n) * CK + ot * 16 + 4 * h] = pp;
    } else {  // pooled
      float v[4];
#pragma unroll
      for (int r = 0; r < 4; ++r) {
        float vv = acc[j][r];
        vv = fmaxf(vv, __shfl_xor(vv, 1));
        vv = fmaxf(vv, __shfl_xor(vv, 2));
        v[r] = vv;
      }
      if ((nl & 3) == 0) {
        if (ot < 4) {  // phi (natural m order)
          int2 pp;
          pp.x = cvtpk(v[0], v[1]);
          pp.y = cvtpk(v[2], v[3]);
          *(int2*)&phi_t[((size_t)b * M_ + m) * CK + (ot - 2) * 16 + 4 * h] = pp;
        } else {  // g (permuted m position)
#pragma unroll
          for (int r = 0; r < 4; ++r) {
            int oc = (ot - 4) * 16 + 4 * h + r;
            g_bf[((size_t)b * CG + oc) * M_ + mp] = f2bf(v[r]);
          }
        }
      }
    }
  }
}

// ---------------- fused flash-attention + out-projection + residual
// r15-proven main loop: 1024 blocks x 128 threads, g LDS double-buffer
// (36,864 B -> 4 blocks/CU), phi in regs, P register-local (permuted g),
// static softmax, one barrier/iter. NEW: transposed epilogue — swap the
// outproj MFMA operands so D is [n][o]; every LDS read stays identical, but
// each lane's 4 acc regs cover 4 CONSECUTIVE n -> float4 out-stores and
// float4 x-loads (16+16 per thread vs 64+64 dwords).
__global__ __launch_bounds__(128, 2) void attn_out_kernel(const short* __restrict__ theta_t,
                                                          const short* __restrict__ phi_t,
                                                          const short* __restrict__ g_bf,
                                                          const float* __restrict__ wo,
                                                          const float* __restrict__ x,
                                                          const float* __restrict__ gamma,
                                                          float* __restrict__ out) {
  __shared__ __align__(16) short lds[18432];  // 36,864 B
  short* g_s = lds;  // 2 x 9216 sh ([c 0..127][m-pos 0..63] stride 72)

  int tid = threadIdx.x;
  int lane = tid & 63, w = tid >> 6;
  int h = lane >> 4, q = lane & 15;
  int bid = blockIdx.x;
  int b = bid & 7, n0 = (bid >> 3) * 32;  // same-b blocks share an XCD L2
  int n = n0 + 16 * w + q;
  float gm = gamma[0];

  bf16x8 qfrag = *(const bf16x8*)&theta_t[((size_t)b * N_ + n) * CK + 8 * h];

  f32x4 Oacc[8];
#pragma unroll
  for (int ct = 0; ct < 8; ++ct) Oacc[ct] = (f32x4){0.f, 0.f, 0.f, 0.f};
  float S = 0.f;
  const f32x4 zero4 = {0.f, 0.f, 0.f, 0.f};

  const short* phi_b = phi_t + (size_t)b * M_ * CK;
  const short* g_b = g_bf + (size_t)b * CG * M_;

  // prologue: phi tile 0 -> regs; g tile 0 -> LDS buf 0 (8 int4/thread)
  int4 pcur[4];
#pragma unroll
  for (int mt = 0; mt < 4; ++mt)
    pcur[mt] = *(const int4*)&phi_b[(16 * mt + q) * CK + 8 * h];
#pragma unroll
  for (int k = 0; k < 8; ++k) {
    int idx = k * 128 + tid;
    int gc = idx >> 3, gmm = idx & 7;
    *(int4*)&g_s[gc * 72 + 8 * gmm] = *(const int4*)&g_b[(size_t)gc * M_ + 8 * gmm];
  }
  __syncthreads();

  for (int it = 0; it < 16; ++it) {
    int cur = it & 1;
    const short* g_c = g_s + cur * 9216;
    // prefetch next tile: phi -> regs, g -> regs (T14)
    int4 pnxt[4], rg[8];
    if (it < 15) {
      int m0n = (it + 1) * 64;
#pragma unroll
      for (int mt = 0; mt < 4; ++mt)
        pnxt[mt] = *(const int4*)&phi_b[(m0n + 16 * mt + q) * CK + 8 * h];
#pragma unroll
      for (int k = 0; k < 8; ++k) {
        int idx = k * 128 + tid;
        int gc = idx >> 3, gmm = idx & 7;
        rg[k] = *(const int4*)&g_b[(size_t)gc * M_ + m0n + 8 * gmm];
      }
    }

    // QK^T from registers: P^T[m][n], own 16-n slice
    f32x4 pt[4];
#pragma unroll
    for (int mt = 0; mt < 4; ++mt)
      pt[mt] = __builtin_amdgcn_mfma_f32_16x16x32_bf16(asbf(pcur[mt]), qfrag, zero4, 0, 0, 0);

    // static softmax numerator; P stays in registers (pk[])
    int2 pk[4];
#pragma unroll
    for (int mt = 0; mt < 4; ++mt) {
      float e0 = __expf(pt[mt][0]);
      float e1 = __expf(pt[mt][1]);
      float e2 = __expf(pt[mt][2]);
      float e3 = __expf(pt[mt][3]);
      S += (e0 + e1) + (e2 + e3);
      pk[mt].x = cvtpk(e0, e1);
      pk[mt].y = cvtpk(e2, e3);
    }

    // PV: O^T[all 128 c][own 16 n]; B-fragment = own pk registers (permuted-g)
    __builtin_amdgcn_s_setprio(1);
#pragma unroll
    for (int kp = 0; kp < 2; ++kp) {
      int4 pfi;
      pfi.x = pk[2 * kp].x;     pfi.y = pk[2 * kp].y;
      pfi.z = pk[2 * kp + 1].x; pfi.w = pk[2 * kp + 1].y;
      bf16x8 pf = asbf(pfi);
#pragma unroll
      for (int ct = 0; ct < 8; ++ct) {
        bf16x8 vf = *(const bf16x8*)&g_c[(16 * ct + q) * 72 + 32 * kp + 8 * h];
        Oacc[ct] = __builtin_amdgcn_mfma_f32_16x16x32_bf16(vf, pf, Oacc[ct], 0, 0, 0);
      }
    }
    __builtin_amdgcn_s_setprio(0);

    // write next g tile into the spare buffer, swap phi regs, one barrier
    if (it < 15) {
      int nxt = cur ^ 1;
#pragma unroll
      for (int k = 0; k < 8; ++k) {
        int idx = k * 128 + tid;
        int gc = idx >> 3, gmm = idx & 7;
        *(int4*)&g_s[nxt * 9216 + gc * 72 + 8 * gmm] = rg[k];
      }
#pragma unroll
      for (int mt = 0; mt < 4; ++mt) pcur[mt] = pnxt[mt];
    }
    __syncthreads();
  }

  // cross-lane denominator reduce (once)
  S += __shfl_xor(S, 16);
  S += __shfl_xor(S, 32);

  // ---- epilogue: O -> LDS; w_o staged in four 64-row quarters.
  // Transposed MFMA: D[n][o] = mfma(A=ot rows n, B=wo cols o) — reads
  // identical to the r15 epilogue (A/B fragments share the per-lane layout),
  // only the operand order and the store indexing change.
  short* ot_s = lds;           // 32 n x stride 136 = 4352 sh
  short* wo_s = lds + 4352;    // 64 o x 128 c = 8192 sh, swizzle g^(o&7)
  float rS = 1.f / S;
  int nloc = 16 * w + q;
#pragma unroll
  for (int ct = 0; ct < 8; ++ct) {
    int2 pp;
    pp.x = cvtpk(Oacc[ct][0] * rS, Oacc[ct][1] * rS);
    pp.y = cvtpk(Oacc[ct][2] * rS, Oacc[ct][3] * rS);
    *(int2*)&ot_s[nloc * 136 + 16 * ct + 4 * h] = pp;
  }

#pragma unroll
  for (int tq = 0; tq < 4; ++tq) {
    // stage w_o rows [64*tq, 64*tq+64) from f32
#pragma unroll
    for (int rep = 0; rep < 8; ++rep) {
      int idx = rep * 128 + tid;
      int ol = idx >> 4, gp = idx & 15;
      const float* src = wo + (size_t)(64 * tq + ol) * 128 + gp * 8;
      float4 f0 = *(const float4*)src;
      float4 f1 = *(const float4*)(src + 4);
      int4 pk2;
      pk2.x = cvtpk(f0.x, f0.y); pk2.y = cvtpk(f0.z, f0.w);
      pk2.z = cvtpk(f1.x, f1.y); pk2.w = cvtpk(f1.z, f1.w);
      *(int4*)&wo_s[ol * 128 + ((gp ^ (ol & 7)) * 8)] = pk2;
    }
    __syncthreads();

    f32x4 acc[4];
#pragma unroll
    for (int j = 0; j < 4; ++j) acc[j] = (f32x4){0.f, 0.f, 0.f, 0.f};

#pragma unroll
    for (int ks = 0; ks < 4; ++ks) {
      // A-fragment: O rows n (own wave's 16 n), k = c
      bf16x8 ofr = *(const bf16x8*)&ot_s[(16 * w + q) * 136 + 32 * ks + 8 * h];
#pragma unroll
      for (int j = 0; j < 4; ++j) {
        int ol = 16 * j + q;
        // B-fragment: wo^T cols o, k = c (same bytes as the old A read)
        bf16x8 wfr = *(const bf16x8*)&wo_s[ol * 128 + (((4 * ks + h) ^ (ol & 7)) * 8)];
        acc[j] = __builtin_amdgcn_mfma_f32_16x16x32_bf16(ofr, wfr, acc[j], 0, 0, 0);
      }
    }

    // D[row=n][col=o]: lane (h,q) reg r -> n = n0+16w+4h+r (consecutive!),
    // o = 64tq+16j+q  ->  float4 store + float4 residual load
#pragma unroll
    for (int j = 0; j < 4; ++j) {
      int o = 64 * tq + 16 * j + q;
      size_t idx = ((size_t)b * C_ + o) * N_ + n0 + 16 * w + 4 * h;
      float4 xv = *(const float4*)&x[idx];
      float4 ov;
      ov.x = gm * acc[j][0] + xv.x;
      ov.y = gm * acc[j][1] + xv.y;
      ov.z = gm * acc[j][2] + xv.z;
      ov.w = gm * acc[j][3] + xv.w;
      *(float4*)&out[idx] = ov;
    }
    __syncthreads();  // wo_s reads done before next quarter's restage
  }
}

extern "C" void kernel_launch(void* const* d_in, const int* in_sizes, int n_in,
                              void* d_out, int out_size, void* d_ws, size_t ws_size,
                              hipStream_t stream) {
  const float* x = (const float*)d_in[0];
  const float* wt = (const float*)d_in[1];
  const float* wp = (const float*)d_in[2];
  const float* wg = (const float*)d_in[3];
  const float* wo = (const float*)d_in[4];
  const float* gamma = (const float*)d_in[5];
  float* out = (float*)d_out;

  short* theta_t = (short*)d_ws;                       // 8*4096*32
  short* phi_t = theta_t + (size_t)B_ * N_ * CK;       // 8*1024*32
  short* g_bf = phi_t + (size_t)B_ * M_ * CK;          // 8*128*1024

  proj_kernel<<<dim3(64, 8), 512, 0, stream>>>(x, wt, wp, wg, theta_t, phi_t, g_bf);
  attn_out_kernel<<<dim3(1024), 128, 0, stream>>>(theta_t, phi_t, g_bf, wo, x, gamma, out);
}

// Round 18
// 53.178 us; speedup vs baseline: 1.8299x; 1.0542x over previous
//
#include <hip/hip_runtime.h>

#define B_ 8
#define C_ 256
#define N_ 4096
#define CK 32
#define CG 128
#define M_ 1024

typedef __attribute__((ext_vector_type(8))) short bf16x8;
typedef __attribute__((ext_vector_type(4))) float f32x4;

__device__ __forceinline__ short f2bf(float f) {
  union { float f; unsigned u; } v; v.f = f;
  unsigned r = (v.u + 0x7FFF + ((v.u >> 16) & 1)) >> 16;  // RNE
  return (short)r;
}
__device__ __forceinline__ int cvtpk(float lo, float hi) {
  int r;
  asm("v_cvt_pk_bf16_f32 %0, %1, %2" : "=v"(r) : "v"(lo), "v"(hi));
  return r;
}
__device__ __forceinline__ bf16x8 asbf(int4 v) {
  union { int4 i; bf16x8 b; } u; u.i = v; return u.b;
}
// async global->LDS, 16 B per lane; LDS dest = wave-uniform base + lane*16
__device__ __forceinline__ void gload_lds16(const void* g, void* l) {
  __builtin_amdgcn_global_load_lds(
      (const __attribute__((address_space(1))) void*)g,
      (__attribute__((address_space(3))) void*)l, 16, 0, 0);
}

// ---------------- fused projection: theta (unpooled) + phi/g (2x2 maxpooled)
// g is written with the J<->h m-bit permutation so attention's PV B-operand
// (P) is register-local.
__global__ __launch_bounds__(512) void proj_kernel(const float* __restrict__ x,
                                                   const float* __restrict__ wt,
                                                   const float* __restrict__ wp,
                                                   const float* __restrict__ wg,
                                                   short* __restrict__ theta_t,
                                                   short* __restrict__ phi_t,
                                                   short* __restrict__ g_bf) {
  __shared__ __align__(16) short w_s[192 * 256];  // 96 KB, 16B-group swizzle g^(o&7)
  __shared__ __align__(16) short x_s[64 * 256];   // 32 KB, 16B-group swizzle g^(nl&7)
  int tid = threadIdx.x;
  int bx = blockIdx.x, b = blockIdx.y;
  int t = bx >> 1, half = bx & 1;

#pragma unroll
  for (int rep = 0; rep < 12; ++rep) {
    int idx = rep * 512 + tid;
    int o = idx >> 5, gp = idx & 31;
    const float* src = (o < 32) ? (wt + o * 256)
                     : (o < 64) ? (wp + (o - 32) * 256)
                                : (wg + (o - 64) * 256);
    float4 f0 = *(const float4*)(src + gp * 8);
    float4 f1 = *(const float4*)(src + gp * 8 + 4);
    int4 pk;
    pk.x = cvtpk(f0.x, f0.y); pk.y = cvtpk(f0.z, f0.w);
    pk.z = cvtpk(f1.x, f1.y); pk.w = cvtpk(f1.z, f1.w);
    *(int4*)&w_s[o * 256 + ((gp ^ (o & 7)) * 8)] = pk;
  }
  {
    int l = tid & 63, cq = tid >> 6;
    int xoff = l >> 1, dy = l & 1;
    int n = t * 128 + dy * 64 + half * 32 + xoff;
    const float* xb = x + (size_t)b * C_ * N_ + n;
#pragma unroll
    for (int rep = 0; rep < 2; ++rep) {
      int ch = cq + rep * 8;
      int c0 = ch * 16;
      float f[16];
#pragma unroll
      for (int i = 0; i < 16; ++i) f[i] = xb[(size_t)(c0 + i) * N_];
      int4 pa, pb;
      pa.x = cvtpk(f[0], f[1]);   pa.y = cvtpk(f[2], f[3]);
      pa.z = cvtpk(f[4], f[5]);   pa.w = cvtpk(f[6], f[7]);
      pb.x = cvtpk(f[8], f[9]);   pb.y = cvtpk(f[10], f[11]);
      pb.z = cvtpk(f[12], f[13]); pb.w = cvtpk(f[14], f[15]);
      *(int4*)&x_s[l * 256 + (((2 * ch) ^ (l & 7)) * 8)] = pa;
      *(int4*)&x_s[l * 256 + (((2 * ch + 1) ^ (l & 7)) * 8)] = pb;
    }
  }
  __syncthreads();

  int lane = tid & 63, w = tid >> 6;
  int h = lane >> 4, q = lane & 15;
  int ns = w & 3, ow = w >> 2;
  f32x4 acc[6];
#pragma unroll
  for (int j = 0; j < 6; ++j) acc[j] = (f32x4){0.f, 0.f, 0.f, 0.f};

  int nl = 16 * ns + q;
#pragma unroll
  for (int ks = 0; ks < 8; ++ks) {
    bf16x8 bfr = *(const bf16x8*)&x_s[nl * 256 + (((4 * ks + h) ^ (nl & 7)) * 8)];
#pragma unroll
    for (int j = 0; j < 6; ++j) {
      int o = 16 * (6 * ow + j) + q;
      bf16x8 afr = *(const bf16x8*)&w_s[o * 256 + (((4 * ks + h) ^ (o & 7)) * 8)];
      acc[j] = __builtin_amdgcn_mfma_f32_16x16x32_bf16(afr, bfr, acc[j], 0, 0, 0);
    }
  }

  int xoff = nl >> 1, dy = nl & 1;
  int n = t * 128 + dy * 64 + half * 32 + xoff;
  int m = t * 32 + half * 16 + (nl >> 2);
  // permuted g position: swap the J (bit4) and h (bits3:2) fields of m
  int mp = (m & ~31) | (((m >> 2) & 3) << 3) | (((m >> 4) & 1) << 2) | (m & 3);
#pragma unroll
  for (int j = 0; j < 6; ++j) {
    int ot = 6 * ow + j;
    if (ot < 2) {  // theta, unpooled
      int2 pp;
      pp.x = cvtpk(acc[j][0], acc[j][1]);
      pp.y = cvtpk(acc[j][2], acc[j][3]);
      *(int2*)&theta_t[((size_t)b * N_ + n) * CK + ot * 16 + 4 * h] = pp;
    } else {  // pooled
      float v[4];
#pragma unroll
      for (int r = 0; r < 4; ++r) {
        float vv = acc[j][r];
        vv = fmaxf(vv, __shfl_xor(vv, 1));
        vv = fmaxf(vv, __shfl_xor(vv, 2));
        v[r] = vv;
      }
      if ((nl & 3) == 0) {
        if (ot < 4) {  // phi (natural m order)
          int2 pp;
          pp.x = cvtpk(v[0], v[1]);
          pp.y = cvtpk(v[2], v[3]);
          *(int2*)&phi_t[((size_t)b * M_ + m) * CK + (ot - 2) * 16 + 4 * h] = pp;
        } else {  // g (permuted m position)
#pragma unroll
          for (int r = 0; r < 4; ++r) {
            int oc = (ot - 4) * 16 + 4 * h + r;
            g_bf[((size_t)b * CG + oc) * M_ + mp] = f2bf(v[r]);
          }
        }
      }
    }
  }
}

// ---------------- fused flash-attention + out-projection + residual
// r15 main loop with DMA staging: g tile staged via global_load_lds (16 B,
// linear LDS dest per m104), bank-spread via T2 XOR swizzle applied on the
// PRE-SWIZZLED GLOBAL SOURCE (m173) and matched on the PV read. Removes all
// staging ds_writes + 32 staging VGPRs + the end-of-iter load-wait->write
// chain (DMA overlaps the whole iteration; pre-barrier vmcnt drain has
// ~2000 cyc slack). 1024 blocks x 128 threads, phi in regs, P register-local
// (permuted g), static softmax, one barrier/iter.
__global__ __launch_bounds__(128, 2) void attn_out_kernel(const short* __restrict__ theta_t,
                                                          const short* __restrict__ phi_t,
                                                          const short* __restrict__ g_bf,
                                                          const float* __restrict__ wo,
                                                          const float* __restrict__ x,
                                                          const float* __restrict__ gamma,
                                                          float* __restrict__ out) {
  __shared__ __align__(16) short lds[16384];  // 32,768 B
  short* g_s = lds;  // 2 x 8192 sh ([c 0..127][m 64] stride 64, XOR-swizzled chunks)

  int tid = threadIdx.x;
  int lane = tid & 63, w = tid >> 6;
  int h = lane >> 4, q = lane & 15;
  int bid = blockIdx.x;
  int b = bid & 7, n0 = (bid >> 3) * 32;  // same-b blocks share an XCD L2
  int n = n0 + 16 * w + q;
  float gm = gamma[0];

  bf16x8 qfrag = *(const bf16x8*)&theta_t[((size_t)b * N_ + n) * CK + 8 * h];

  f32x4 Oacc[8];
#pragma unroll
  for (int ct = 0; ct < 8; ++ct) Oacc[ct] = (f32x4){0.f, 0.f, 0.f, 0.f};
  float S = 0.f;
  const f32x4 zero4 = {0.f, 0.f, 0.f, 0.f};

  const short* phi_b = phi_t + (size_t)b * M_ * CK;
  const short* g_b = g_bf + (size_t)b * CG * M_;

  // staging geometry: lane writes LDS linear slot (k*128+tid)*16 B; the
  // source m-chunk is XOR-pre-swizzled so reads can bank-spread.
  int srow = tid >> 3;                       // c-row within k-slab (8 rows/slab of 16)
  int sgrp = (tid & 7) ^ (srow & 7);         // pre-swizzled source chunk
  size_t srcoff = (size_t)srow * M_ + sgrp * 8;  // + k*16*M_ per slab
  int wbase = tid & ~63;                     // wave-uniform lane base

  // prologue: phi tile 0 -> regs; g tile 0 -> LDS buf 0 via DMA
  int4 pcur[4];
#pragma unroll
  for (int mt = 0; mt < 4; ++mt)
    pcur[mt] = *(const int4*)&phi_b[(16 * mt + q) * CK + 8 * h];
#pragma unroll
  for (int k = 0; k < 8; ++k)
    gload_lds16(g_b + (size_t)k * 16 * M_ + srcoff,
                &g_s[(k * 128 + wbase) * 8]);
  __syncthreads();

  for (int it = 0; it < 16; ++it) {
    int cur = it & 1;
    const short* g_c = g_s + cur * 8192;
    // issue next tile's DMA staging + phi prefetch (overlaps this iter)
    int4 pnxt[4];
    if (it < 15) {
      int m0n = (it + 1) * 64;
#pragma unroll
      for (int k = 0; k < 8; ++k)
        gload_lds16(g_b + (size_t)k * 16 * M_ + srcoff + m0n,
                    &g_s[(cur ^ 1) * 8192 + (k * 128 + wbase) * 8]);
#pragma unroll
      for (int mt = 0; mt < 4; ++mt)
        pnxt[mt] = *(const int4*)&phi_b[(m0n + 16 * mt + q) * CK + 8 * h];
    }

    // QK^T from registers: P^T[m][n], own 16-n slice
    f32x4 pt[4];
#pragma unroll
    for (int mt = 0; mt < 4; ++mt)
      pt[mt] = __builtin_amdgcn_mfma_f32_16x16x32_bf16(asbf(pcur[mt]), qfrag, zero4, 0, 0, 0);

    // static softmax numerator; P stays in registers (pk[])
    int2 pk[4];
#pragma unroll
    for (int mt = 0; mt < 4; ++mt) {
      float e0 = __expf(pt[mt][0]);
      float e1 = __expf(pt[mt][1]);
      float e2 = __expf(pt[mt][2]);
      float e3 = __expf(pt[mt][3]);
      S += (e0 + e1) + (e2 + e3);
      pk[mt].x = cvtpk(e0, e1);
      pk[mt].y = cvtpk(e2, e3);
    }

    // PV: O^T[all 128 c][own 16 n]; B = own pk regs; A = swizzled LDS read
    __builtin_amdgcn_s_setprio(1);
#pragma unroll
    for (int kp = 0; kp < 2; ++kp) {
      int4 pfi;
      pfi.x = pk[2 * kp].x;     pfi.y = pk[2 * kp].y;
      pfi.z = pk[2 * kp + 1].x; pfi.w = pk[2 * kp + 1].y;
      bf16x8 pf = asbf(pfi);
#pragma unroll
      for (int ct = 0; ct < 8; ++ct) {
        bf16x8 vf = *(const bf16x8*)&g_c[(16 * ct + q) * 64 +
                                         (((4 * kp + h) ^ (q & 7)) * 8)];
        Oacc[ct] = __builtin_amdgcn_mfma_f32_16x16x32_bf16(vf, pf, Oacc[ct], 0, 0, 0);
      }
    }
    __builtin_amdgcn_s_setprio(0);

    if (it < 15) {
#pragma unroll
      for (int mt = 0; mt < 4; ++mt) pcur[mt] = pnxt[mt];
    }
    __syncthreads();  // drains DMA (compiler vmcnt) + swaps buffers
  }

  // cross-lane denominator reduce (once)
  S += __shfl_xor(S, 16);
  S += __shfl_xor(S, 32);

  // ---- epilogue (r15-proven): O -> LDS; w_o staged in four 64-row quarters
  short* ot_s = lds;           // 32 n x stride 136 = 4352 sh
  short* wo_s = lds + 4352;    // 64 o x 128 c = 8192 sh, swizzle g^(o&7)
  float rS = 1.f / S;
  int nloc = 16 * w + q;
#pragma unroll
  for (int ct = 0; ct < 8; ++ct) {
    int2 pp;
    pp.x = cvtpk(Oacc[ct][0] * rS, Oacc[ct][1] * rS);
    pp.y = cvtpk(Oacc[ct][2] * rS, Oacc[ct][3] * rS);
    *(int2*)&ot_s[nloc * 136 + 16 * ct + 4 * h] = pp;
  }

#pragma unroll
  for (int tq = 0; tq < 4; ++tq) {
    // stage w_o rows [64*tq, 64*tq+64) from f32
#pragma unroll
    for (int rep = 0; rep < 8; ++rep) {
      int idx = rep * 128 + tid;
      int ol = idx >> 4, gp = idx & 15;
      const float* src = wo + (size_t)(64 * tq + ol) * 128 + gp * 8;
      float4 f0 = *(const float4*)src;
      float4 f1 = *(const float4*)(src + 4);
      int4 pk2;
      pk2.x = cvtpk(f0.x, f0.y); pk2.y = cvtpk(f0.z, f0.w);
      pk2.z = cvtpk(f1.x, f1.y); pk2.w = cvtpk(f1.z, f1.w);
      *(int4*)&wo_s[ol * 128 + ((gp ^ (ol & 7)) * 8)] = pk2;
    }
    __syncthreads();

    f32x4 acc[4];
#pragma unroll
    for (int j = 0; j < 4; ++j) acc[j] = (f32x4){0.f, 0.f, 0.f, 0.f};

#pragma unroll
    for (int ks = 0; ks < 4; ++ks) {
      bf16x8 bfr = *(const bf16x8*)&ot_s[(16 * w + q) * 136 + 32 * ks + 8 * h];
#pragma unroll
      for (int j = 0; j < 4; ++j) {
        int ol = 16 * j + q;
        bf16x8 afr = *(const bf16x8*)&wo_s[ol * 128 + (((4 * ks + h) ^ (ol & 7)) * 8)];
        acc[j] = __builtin_amdgcn_mfma_f32_16x16x32_bf16(afr, bfr, acc[j], 0, 0, 0);
      }
    }

#pragma unroll
    for (int j = 0; j < 4; ++j)
#pragma unroll
      for (int r = 0; r < 4; ++r) {
        int o = 64 * tq + 16 * j + 4 * h + r;
        size_t idx = ((size_t)b * C_ + o) * N_ + n;
        out[idx] = gm * acc[j][r] + x[idx];
      }
    __syncthreads();  // wo_s reads done before next quarter's restage
  }
}

extern "C" void kernel_launch(void* const* d_in, const int* in_sizes, int n_in,
                              void* d_out, int out_size, void* d_ws, size_t ws_size,
                              hipStream_t stream) {
  const float* x = (const float*)d_in[0];
  const float* wt = (const float*)d_in[1];
  const float* wp = (const float*)d_in[2];
  const float* wg = (const float*)d_in[3];
  const float* wo = (const float*)d_in[4];
  const float* gamma = (const float*)d_in[5];
  float* out = (float*)d_out;

  short* theta_t = (short*)d_ws;                       // 8*4096*32
  short* phi_t = theta_t + (size_t)B_ * N_ * CK;       // 8*1024*32
  short* g_bf = phi_t + (size_t)B_ * M_ * CK;          // 8*128*1024

  proj_kernel<<<dim3(64, 8), 512, 0, stream>>>(x, wt, wp, wg, theta_t, phi_t, g_bf);
  attn_out_kernel<<<dim3(1024), 128, 0, stream>>>(theta_t, phi_t, g_bf, wo, x, gamma, out);
}

// Round 19
// 49.466 us; speedup vs baseline: 1.9672x; 1.0750x over previous
//
#include <hip/hip_runtime.h>

#define B_ 8
#define C_ 256
#define N_ 4096
#define CK 32
#define CG 128
#define M_ 1024

typedef __attribute__((ext_vector_type(8))) short bf16x8;
typedef __attribute__((ext_vector_type(4))) float f32x4;

__device__ __forceinline__ short f2bf(float f) {
  union { float f; unsigned u; } v; v.f = f;
  unsigned r = (v.u + 0x7FFF + ((v.u >> 16) & 1)) >> 16;  // RNE
  return (short)r;
}
__device__ __forceinline__ int cvtpk(float lo, float hi) {
  int r;
  asm("v_cvt_pk_bf16_f32 %0, %1, %2" : "=v"(r) : "v"(lo), "v"(hi));
  return r;
}
__device__ __forceinline__ bf16x8 asbf(int4 v) {
  union { int4 i; bf16x8 b; } u; u.i = v; return u.b;
}
// async global->LDS, 16 B per lane; LDS dest = wave-uniform base + lane*16
__device__ __forceinline__ void gload_lds16(const void* g, void* l) {
  __builtin_amdgcn_global_load_lds(
      (const __attribute__((address_space(1))) void*)g,
      (__attribute__((address_space(3))) void*)l, 16, 0, 0);
}

// ---------------- fused projection: theta (unpooled) + phi/g (2x2 maxpooled)
// g is written with the J<->h m-bit permutation so attention's PV B-operand
// (P) is register-local.
__global__ __launch_bounds__(512) void proj_kernel(const float* __restrict__ x,
                                                   const float* __restrict__ wt,
                                                   const float* __restrict__ wp,
                                                   const float* __restrict__ wg,
                                                   short* __restrict__ theta_t,
                                                   short* __restrict__ phi_t,
                                                   short* __restrict__ g_bf) {
  __shared__ __align__(16) short w_s[192 * 256];  // 96 KB, 16B-group swizzle g^(o&7)
  __shared__ __align__(16) short x_s[64 * 256];   // 32 KB, 16B-group swizzle g^(nl&7)
  int tid = threadIdx.x;
  int bx = blockIdx.x, b = blockIdx.y;
  int t = bx >> 1, half = bx & 1;

#pragma unroll
  for (int rep = 0; rep < 12; ++rep) {
    int idx = rep * 512 + tid;
    int o = idx >> 5, gp = idx & 31;
    const float* src = (o < 32) ? (wt + o * 256)
                     : (o < 64) ? (wp + (o - 32) * 256)
                                : (wg + (o - 64) * 256);
    float4 f0 = *(const float4*)(src + gp * 8);
    float4 f1 = *(const float4*)(src + gp * 8 + 4);
    int4 pk;
    pk.x = cvtpk(f0.x, f0.y); pk.y = cvtpk(f0.z, f0.w);
    pk.z = cvtpk(f1.x, f1.y); pk.w = cvtpk(f1.z, f1.w);
    *(int4*)&w_s[o * 256 + ((gp ^ (o & 7)) * 8)] = pk;
  }
  {
    int l = tid & 63, cq = tid >> 6;
    int xoff = l >> 1, dy = l & 1;
    int n = t * 128 + dy * 64 + half * 32 + xoff;
    const float* xb = x + (size_t)b * C_ * N_ + n;
#pragma unroll
    for (int rep = 0; rep < 2; ++rep) {
      int ch = cq + rep * 8;
      int c0 = ch * 16;
      float f[16];
#pragma unroll
      for (int i = 0; i < 16; ++i) f[i] = xb[(size_t)(c0 + i) * N_];
      int4 pa, pb;
      pa.x = cvtpk(f[0], f[1]);   pa.y = cvtpk(f[2], f[3]);
      pa.z = cvtpk(f[4], f[5]);   pa.w = cvtpk(f[6], f[7]);
      pb.x = cvtpk(f[8], f[9]);   pb.y = cvtpk(f[10], f[11]);
      pb.z = cvtpk(f[12], f[13]); pb.w = cvtpk(f[14], f[15]);
      *(int4*)&x_s[l * 256 + (((2 * ch) ^ (l & 7)) * 8)] = pa;
      *(int4*)&x_s[l * 256 + (((2 * ch + 1) ^ (l & 7)) * 8)] = pb;
    }
  }
  __syncthreads();

  int lane = tid & 63, w = tid >> 6;
  int h = lane >> 4, q = lane & 15;
  int ns = w & 3, ow = w >> 2;
  f32x4 acc[6];
#pragma unroll
  for (int j = 0; j < 6; ++j) acc[j] = (f32x4){0.f, 0.f, 0.f, 0.f};

  int nl = 16 * ns + q;
#pragma unroll
  for (int ks = 0; ks < 8; ++ks) {
    bf16x8 bfr = *(const bf16x8*)&x_s[nl * 256 + (((4 * ks + h) ^ (nl & 7)) * 8)];
#pragma unroll
    for (int j = 0; j < 6; ++j) {
      int o = 16 * (6 * ow + j) + q;
      bf16x8 afr = *(const bf16x8*)&w_s[o * 256 + (((4 * ks + h) ^ (o & 7)) * 8)];
      acc[j] = __builtin_amdgcn_mfma_f32_16x16x32_bf16(afr, bfr, acc[j], 0, 0, 0);
    }
  }

  int xoff = nl >> 1, dy = nl & 1;
  int n = t * 128 + dy * 64 + half * 32 + xoff;
  int m = t * 32 + half * 16 + (nl >> 2);
  // permuted g position: swap the J (bit4) and h (bits3:2) fields of m
  int mp = (m & ~31) | (((m >> 2) & 3) << 3) | (((m >> 4) & 1) << 2) | (m & 3);
#pragma unroll
  for (int j = 0; j < 6; ++j) {
    int ot = 6 * ow + j;
    if (ot < 2) {  // theta, unpooled
      int2 pp;
      pp.x = cvtpk(acc[j][0], acc[j][1]);
      pp.y = cvtpk(acc[j][2], acc[j][3]);
      *(int2*)&theta_t[((size_t)b * N_ + n) * CK + ot * 16 + 4 * h] = pp;
    } else {  // pooled
      float v[4];
#pragma unroll
      for (int r = 0; r < 4; ++r) {
        float vv = acc[j][r];
        vv = fmaxf(vv, __shfl_xor(vv, 1));
        vv = fmaxf(vv, __shfl_xor(vv, 2));
        v[r] = vv;
      }
      if ((nl & 3) == 0) {
        if (ot < 4) {  // phi (natural m order)
          int2 pp;
          pp.x = cvtpk(v[0], v[1]);
          pp.y = cvtpk(v[2], v[3]);
          *(int2*)&phi_t[((size_t)b * M_ + m) * CK + (ot - 2) * 16 + 4 * h] = pp;
        } else {  // g (permuted m position)
#pragma unroll
          for (int r = 0; r < 4; ++r) {
            int oc = (ot - 4) * 16 + 4 * h + r;
            g_bf[((size_t)b * CG + oc) * M_ + mp] = f2bf(v[r]);
          }
        }
      }
    }
  }
}

// ---------------- fused flash-attention + out-projection + residual
// In-block m-split x2 for TLP: block = 8 waves = 4 n-slices x 2 m-halves
// (64 queries); each m-half group runs an independent DMA-staged,
// double-buffered V stream over its 512 m's (8 iters). Grid 512 -> 2 blocks/CU
// x 8 waves = 16 waves/CU (2x r18). Static softmax makes the half-merge a pure
// ADD of unnormalized O and S through LDS (V region is dead by then).
// P register-local (permuted g), phi in regs, one barrier/iter.
__global__ __launch_bounds__(512, 4) void attn_out_kernel(const short* __restrict__ theta_t,
                                                          const short* __restrict__ phi_t,
                                                          const short* __restrict__ g_bf,
                                                          const float* __restrict__ wo,
                                                          const float* __restrict__ x,
                                                          const float* __restrict__ gamma,
                                                          float* __restrict__ out) {
  __shared__ __align__(16) short lds[32768];  // 65,536 B
  // main loop: per half, 2 bufs x 8192 sh ([c 0..127][m 64] stride 64, swz chunks)

  int tid = threadIdx.x;
  int lane = tid & 63, w = tid >> 6;
  int h = lane >> 4, q = lane & 15;
  int w_n = w & 3, w_m = w >> 2;
  int bid = blockIdx.x;
  int b = bid & 7, n0 = (bid >> 3) * 64;  // same-b blocks share an XCD L2
  int n = n0 + 16 * w_n + q;
  float gm = gamma[0];

  bf16x8 qfrag = *(const bf16x8*)&theta_t[((size_t)b * N_ + n) * CK + 8 * h];

  f32x4 Oacc[8];
#pragma unroll
  for (int ct = 0; ct < 8; ++ct) Oacc[ct] = (f32x4){0.f, 0.f, 0.f, 0.f};
  float S = 0.f;
  const f32x4 zero4 = {0.f, 0.f, 0.f, 0.f};

  const short* phi_b = phi_t + (size_t)b * M_ * CK;
  const short* g_b = g_bf + (size_t)b * CG * M_;

  // staging geometry (per m-half: 256 threads stage 128c x 64m = 16 KB via
  // 4 gload_lds16 each; linear LDS dest, XOR-pre-swizzled global source)
  int ht = tid & 255;
  int srow = ht >> 3;                      // c-row within 32-row k-slab
  int sgrp = (ht & 7) ^ (srow & 7);        // pre-swizzled source m-chunk
  size_t srcoff = (size_t)srow * M_ + sgrp * 8 + (size_t)w_m * 512;
  int wslot = ht & ~63;                    // wave-uniform lane base
  short* gbase = lds + w_m * 16384;
  int mbase = w_m * 512;

  // prologue: phi tile 0 -> regs; V tile 0 -> LDS buf 0 via DMA
  int4 pcur[4];
#pragma unroll
  for (int mt = 0; mt < 4; ++mt)
    pcur[mt] = *(const int4*)&phi_b[(mbase + 16 * mt + q) * CK + 8 * h];
#pragma unroll
  for (int k = 0; k < 4; ++k)
    gload_lds16(g_b + (size_t)k * 32 * M_ + srcoff,
                &gbase[(k * 256 + wslot) * 8]);
  __syncthreads();

  for (int it = 0; it < 8; ++it) {
    int cur = it & 1;
    const short* g_c = gbase + cur * 8192;
    // issue next tile's DMA staging + phi prefetch (overlaps this iter)
    int4 pnxt[4];
    if (it < 7) {
      int m0n = (it + 1) * 64;
#pragma unroll
      for (int k = 0; k < 4; ++k)
        gload_lds16(g_b + (size_t)k * 32 * M_ + srcoff + m0n,
                    &gbase[(cur ^ 1) * 8192 + (k * 256 + wslot) * 8]);
#pragma unroll
      for (int mt = 0; mt < 4; ++mt)
        pnxt[mt] = *(const int4*)&phi_b[(mbase + m0n + 16 * mt + q) * CK + 8 * h];
    }

    // QK^T from registers: P^T[m][n], own 16-n slice, own m-half
    f32x4 pt[4];
#pragma unroll
    for (int mt = 0; mt < 4; ++mt)
      pt[mt] = __builtin_amdgcn_mfma_f32_16x16x32_bf16(asbf(pcur[mt]), qfrag, zero4, 0, 0, 0);

    // static softmax numerator; P stays in registers (pk[])
    int2 pk[4];
#pragma unroll
    for (int mt = 0; mt < 4; ++mt) {
      float e0 = __expf(pt[mt][0]);
      float e1 = __expf(pt[mt][1]);
      float e2 = __expf(pt[mt][2]);
      float e3 = __expf(pt[mt][3]);
      S += (e0 + e1) + (e2 + e3);
      pk[mt].x = cvtpk(e0, e1);
      pk[mt].y = cvtpk(e2, e3);
    }

    // PV: O^T[all 128 c][own 16 n]; B = own pk regs; A = swizzled LDS read
    __builtin_amdgcn_s_setprio(1);
#pragma unroll
    for (int kp = 0; kp < 2; ++kp) {
      int4 pfi;
      pfi.x = pk[2 * kp].x;     pfi.y = pk[2 * kp].y;
      pfi.z = pk[2 * kp + 1].x; pfi.w = pk[2 * kp + 1].y;
      bf16x8 pf = asbf(pfi);
#pragma unroll
      for (int ct = 0; ct < 8; ++ct) {
        bf16x8 vf = *(const bf16x8*)&g_c[(16 * ct + q) * 64 +
                                         (((4 * kp + h) ^ (q & 7)) * 8)];
        Oacc[ct] = __builtin_amdgcn_mfma_f32_16x16x32_bf16(vf, pf, Oacc[ct], 0, 0, 0);
      }
    }
    __builtin_amdgcn_s_setprio(0);

    if (it < 7) {
#pragma unroll
      for (int mt = 0; mt < 4; ++mt) pcur[mt] = pnxt[mt];
    }
    __syncthreads();  // drains DMA (compiler vmcnt) + swaps buffers
  }

  // per-wave denominator reduce (each lane -> full half-sum for its n)
  S += __shfl_xor(S, 16);
  S += __shfl_xor(S, 32);

  // ---- half-merge through LDS (V region dead): O_unnorm and S just ADD
  float* otf = (float*)lds;        // [64 n][132 f32]
  float* s_f = otf + 64 * 132;     // 64 floats
  int row = 16 * w_n + q;
  if (w_m == 1) {
#pragma unroll
    for (int ct = 0; ct < 8; ++ct)
      *(f32x4*)&otf[row * 132 + 16 * ct + 4 * h] = Oacc[ct];
    if (h == 0) s_f[row] = S;
  }
  __syncthreads();
  if (w_m == 0) {
#pragma unroll
    for (int ct = 0; ct < 8; ++ct)
      Oacc[ct] += *(const f32x4*)&otf[row * 132 + 16 * ct + 4 * h];
    S += s_f[row];
  }
  float rS = 1.f / S;
  __syncthreads();  // otf reads done before ot_s overwrites the region

  // ---- epilogue: normalized O -> ot_s (w_m=0 waves); w_o in 64-row quarters
  short* ot_s = lds;            // 64 n x stride 136 = 8704 sh
  short* wo_s = lds + 8704;     // 64 o x 128 c = 8192 sh, swizzle g^(o&7)
  if (w_m == 0) {
#pragma unroll
    for (int ct = 0; ct < 8; ++ct) {
      int2 pp;
      pp.x = cvtpk(Oacc[ct][0] * rS, Oacc[ct][1] * rS);
      pp.y = cvtpk(Oacc[ct][2] * rS, Oacc[ct][3] * rS);
      *(int2*)&ot_s[row * 136 + 16 * ct + 4 * h] = pp;
    }
  }

  int jj = w & 3, np = w >> 2;  // wave: o-tile jj, n-pair np
#pragma unroll
  for (int tq = 0; tq < 4; ++tq) {
    // stage w_o rows [64*tq, 64*tq+64) from f32 (512 threads, 2 int4 each)
#pragma unroll
    for (int rep = 0; rep < 2; ++rep) {
      int idx = rep * 512 + tid;
      int ol = idx >> 4, gp = idx & 15;
      const float* src = wo + (size_t)(64 * tq + ol) * 128 + gp * 8;
      float4 f0 = *(const float4*)src;
      float4 f1 = *(const float4*)(src + 4);
      int4 pk2;
      pk2.x = cvtpk(f0.x, f0.y); pk2.y = cvtpk(f0.z, f0.w);
      pk2.z = cvtpk(f1.x, f1.y); pk2.w = cvtpk(f1.z, f1.w);
      *(int4*)&wo_s[ol * 128 + ((gp ^ (ol & 7)) * 8)] = pk2;
    }
    __syncthreads();

    // wave (jj, np): o-tile 16jj within quarter, n-tiles 2np, 2np+1
    f32x4 acc[2];
    acc[0] = (f32x4){0.f, 0.f, 0.f, 0.f};
    acc[1] = (f32x4){0.f, 0.f, 0.f, 0.f};
#pragma unroll
    for (int ks = 0; ks < 4; ++ks) {
      bf16x8 bfr0 = *(const bf16x8*)&ot_s[(16 * (2 * np) + q) * 136 + 32 * ks + 8 * h];
      bf16x8 bfr1 = *(const bf16x8*)&ot_s[(16 * (2 * np + 1) + q) * 136 + 32 * ks + 8 * h];
      int ol = 16 * jj + q;
      bf16x8 afr = *(const bf16x8*)&wo_s[ol * 128 + (((4 * ks + h) ^ (ol & 7)) * 8)];
      acc[0] = __builtin_amdgcn_mfma_f32_16x16x32_bf16(afr, bfr0, acc[0], 0, 0, 0);
      acc[1] = __builtin_amdgcn_mfma_f32_16x16x32_bf16(afr, bfr1, acc[1], 0, 0, 0);
    }

#pragma unroll
    for (int i = 0; i < 2; ++i)
#pragma unroll
      for (int r = 0; r < 4; ++r) {
        int o = 64 * tq + 16 * jj + 4 * h + r;
        int nn = n0 + 16 * (2 * np + i) + q;
        size_t idx = ((size_t)b * C_ + o) * N_ + nn;
        out[idx] = gm * acc[i][r] + x[idx];
      }
    __syncthreads();  // wo_s reads done before next quarter's restage
  }
}

extern "C" void kernel_launch(void* const* d_in, const int* in_sizes, int n_in,
                              void* d_out, int out_size, void* d_ws, size_t ws_size,
                              hipStream_t stream) {
  const float* x = (const float*)d_in[0];
  const float* wt = (const float*)d_in[1];
  const float* wp = (const float*)d_in[2];
  const float* wg = (const float*)d_in[3];
  const float* wo = (const float*)d_in[4];
  const float* gamma = (const float*)d_in[5];
  float* out = (float*)d_out;

  short* theta_t = (short*)d_ws;                       // 8*4096*32
  short* phi_t = theta_t + (size_t)B_ * N_ * CK;       // 8*1024*32
  short* g_bf = phi_t + (size_t)B_ * M_ * CK;          // 8*128*1024

  proj_kernel<<<dim3(64, 8), 512, 0, stream>>>(x, wt, wp, wg, theta_t, phi_t, g_bf);
  attn_out_kernel<<<dim3(512), 512, 0, stream>>>(theta_t, phi_t, g_bf, wo, x, gamma, out);
}

// Round 21
// 48.599 us; speedup vs baseline: 2.0022x; 1.0178x over previous
//
#include <hip/hip_runtime.h>

#define B_ 8
#define C_ 256
#define N_ 4096
#define CK 32
#define CG 128
#define M_ 1024

typedef __attribute__((ext_vector_type(8))) short bf16x8;
typedef __attribute__((ext_vector_type(4))) float f32x4;

__device__ __forceinline__ short f2bf(float f) {
  union { float f; unsigned u; } v; v.f = f;
  unsigned r = (v.u + 0x7FFF + ((v.u >> 16) & 1)) >> 16;  // RNE
  return (short)r;
}
__device__ __forceinline__ int cvtpk(float lo, float hi) {
  int r;
  asm("v_cvt_pk_bf16_f32 %0, %1, %2" : "=v"(r) : "v"(lo), "v"(hi));
  return r;
}
__device__ __forceinline__ bf16x8 asbf(int4 v) {
  union { int4 i; bf16x8 b; } u; u.i = v; return u.b;
}
// async global->LDS, 16 B per lane; LDS dest = wave-uniform base + lane*16
__device__ __forceinline__ void gload_lds16(const void* g, void* l) {
  __builtin_amdgcn_global_load_lds(
      (const __attribute__((address_space(1))) void*)g,
      (__attribute__((address_space(3))) void*)l, 16, 0, 0);
}

// ---------------- fused projection: theta (unpooled) + phi/g (2x2 maxpooled)
// g is written with the J<->h m-bit permutation so attention's PV B-operand
// (P) is register-local.
__global__ __launch_bounds__(512) void proj_kernel(const float* __restrict__ x,
                                                   const float* __restrict__ wt,
                                                   const float* __restrict__ wp,
                                                   const float* __restrict__ wg,
                                                   short* __restrict__ theta_t,
                                                   short* __restrict__ phi_t,
                                                   short* __restrict__ g_bf) {
  __shared__ __align__(16) short w_s[192 * 256];  // 96 KB, 16B-group swizzle g^(o&7)
  __shared__ __align__(16) short x_s[64 * 256];   // 32 KB, 16B-group swizzle g^(nl&7)
  int tid = threadIdx.x;
  int bx = blockIdx.x, b = blockIdx.y;
  int t = bx >> 1, half = bx & 1;

#pragma unroll
  for (int rep = 0; rep < 12; ++rep) {
    int idx = rep * 512 + tid;
    int o = idx >> 5, gp = idx & 31;
    const float* src = (o < 32) ? (wt + o * 256)
                     : (o < 64) ? (wp + (o - 32) * 256)
                                : (wg + (o - 64) * 256);
    float4 f0 = *(const float4*)(src + gp * 8);
    float4 f1 = *(const float4*)(src + gp * 8 + 4);
    int4 pk;
    pk.x = cvtpk(f0.x, f0.y); pk.y = cvtpk(f0.z, f0.w);
    pk.z = cvtpk(f1.x, f1.y); pk.w = cvtpk(f1.z, f1.w);
    *(int4*)&w_s[o * 256 + ((gp ^ (o & 7)) * 8)] = pk;
  }
  {
    int l = tid & 63, cq = tid >> 6;
    int xoff = l >> 1, dy = l & 1;
    int n = t * 128 + dy * 64 + half * 32 + xoff;
    const float* xb = x + (size_t)b * C_ * N_ + n;
#pragma unroll
    for (int rep = 0; rep < 2; ++rep) {
      int ch = cq + rep * 8;
      int c0 = ch * 16;
      float f[16];
#pragma unroll
      for (int i = 0; i < 16; ++i) f[i] = xb[(size_t)(c0 + i) * N_];
      int4 pa, pb;
      pa.x = cvtpk(f[0], f[1]);   pa.y = cvtpk(f[2], f[3]);
      pa.z = cvtpk(f[4], f[5]);   pa.w = cvtpk(f[6], f[7]);
      pb.x = cvtpk(f[8], f[9]);   pb.y = cvtpk(f[10], f[11]);
      pb.z = cvtpk(f[12], f[13]); pb.w = cvtpk(f[14], f[15]);
      *(int4*)&x_s[l * 256 + (((2 * ch) ^ (l & 7)) * 8)] = pa;
      *(int4*)&x_s[l * 256 + (((2 * ch + 1) ^ (l & 7)) * 8)] = pb;
    }
  }
  __syncthreads();

  int lane = tid & 63, w = tid >> 6;
  int h = lane >> 4, q = lane & 15;
  int ns = w & 3, ow = w >> 2;
  f32x4 acc[6];
#pragma unroll
  for (int j = 0; j < 6; ++j) acc[j] = (f32x4){0.f, 0.f, 0.f, 0.f};

  int nl = 16 * ns + q;
#pragma unroll
  for (int ks = 0; ks < 8; ++ks) {
    bf16x8 bfr = *(const bf16x8*)&x_s[nl * 256 + (((4 * ks + h) ^ (nl & 7)) * 8)];
#pragma unroll
    for (int j = 0; j < 6; ++j) {
      int o = 16 * (6 * ow + j) + q;
      bf16x8 afr = *(const bf16x8*)&w_s[o * 256 + (((4 * ks + h) ^ (o & 7)) * 8)];
      acc[j] = __builtin_amdgcn_mfma_f32_16x16x32_bf16(afr, bfr, acc[j], 0, 0, 0);
    }
  }

  int xoff = nl >> 1, dy = nl & 1;
  int n = t * 128 + dy * 64 + half * 32 + xoff;
  int m = t * 32 + half * 16 + (nl >> 2);
  // permuted g position: swap the J (bit4) and h (bits3:2) fields of m
  int mp = (m & ~31) | (((m >> 2) & 3) << 3) | (((m >> 4) & 1) << 2) | (m & 3);
#pragma unroll
  for (int j = 0; j < 6; ++j) {
    int ot = 6 * ow + j;
    if (ot < 2) {  // theta, unpooled
      int2 pp;
      pp.x = cvtpk(acc[j][0], acc[j][1]);
      pp.y = cvtpk(acc[j][2], acc[j][3]);
      *(int2*)&theta_t[((size_t)b * N_ + n) * CK + ot * 16 + 4 * h] = pp;
    } else {  // pooled
      float v[4];
#pragma unroll
      for (int r = 0; r < 4; ++r) {
        float vv = acc[j][r];
        vv = fmaxf(vv, __shfl_xor(vv, 1));
        vv = fmaxf(vv, __shfl_xor(vv, 2));
        v[r] = vv;
      }
      if ((nl & 3) == 0) {
        if (ot < 4) {  // phi (natural m order)
          int2 pp;
          pp.x = cvtpk(v[0], v[1]);
          pp.y = cvtpk(v[2], v[3]);
          *(int2*)&phi_t[((size_t)b * M_ + m) * CK + (ot - 2) * 16 + 4 * h] = pp;
        } else {  // g (permuted m position)
#pragma unroll
          for (int r = 0; r < 4; ++r) {
            int oc = (ot - 4) * 16 + 4 * h + r;
            g_bf[((size_t)b * CG + oc) * M_ + mp] = f2bf(v[r]);
          }
        }
      }
    }
  }
}

// ---------------- fused flash-attention + out-projection + residual
// r19 main loop (in-block m-split x2: 8 waves = 4n x 2m, DMA-staged dbuf V
// streams, static softmax, P register-local, 16 waves/CU) with a consolidated
// epilogue: wo staged in TWO 128-row halves (r20 bug fixed: staging now
// covers all 128 rows, rep<4). Epilogue barriers 8 -> 3.
__global__ __launch_bounds__(512, 4) void attn_out_kernel(const short* __restrict__ theta_t,
                                                          const short* __restrict__ phi_t,
                                                          const short* __restrict__ g_bf,
                                                          const float* __restrict__ wo,
                                                          const float* __restrict__ x,
                                                          const float* __restrict__ gamma,
                                                          float* __restrict__ out) {
  __shared__ __align__(16) short lds[32768];  // 65,536 B
  // main loop: per half, 2 bufs x 8192 sh ([c 0..127][m 64] stride 64, swz chunks)

  int tid = threadIdx.x;
  int lane = tid & 63, w = tid >> 6;
  int h = lane >> 4, q = lane & 15;
  int w_n = w & 3, w_m = w >> 2;
  int bid = blockIdx.x;
  int b = bid & 7, n0 = (bid >> 3) * 64;  // same-b blocks share an XCD L2
  int n = n0 + 16 * w_n + q;
  float gm = gamma[0];

  bf16x8 qfrag = *(const bf16x8*)&theta_t[((size_t)b * N_ + n) * CK + 8 * h];

  f32x4 Oacc[8];
#pragma unroll
  for (int ct = 0; ct < 8; ++ct) Oacc[ct] = (f32x4){0.f, 0.f, 0.f, 0.f};
  float S = 0.f;
  const f32x4 zero4 = {0.f, 0.f, 0.f, 0.f};

  const short* phi_b = phi_t + (size_t)b * M_ * CK;
  const short* g_b = g_bf + (size_t)b * CG * M_;

  // staging geometry (per m-half: 256 threads stage 128c x 64m = 16 KB via
  // 4 gload_lds16 each; linear LDS dest, XOR-pre-swizzled global source)
  int ht = tid & 255;
  int srow = ht >> 3;                      // c-row within 32-row k-slab
  int sgrp = (ht & 7) ^ (srow & 7);        // pre-swizzled source m-chunk
  size_t srcoff = (size_t)srow * M_ + sgrp * 8 + (size_t)w_m * 512;
  int wslot = ht & ~63;                    // wave-uniform lane base
  short* gbase = lds + w_m * 16384;
  int mbase = w_m * 512;

  // prologue: phi tile 0 -> regs; V tile 0 -> LDS buf 0 via DMA
  int4 pcur[4];
#pragma unroll
  for (int mt = 0; mt < 4; ++mt)
    pcur[mt] = *(const int4*)&phi_b[(mbase + 16 * mt + q) * CK + 8 * h];
#pragma unroll
  for (int k = 0; k < 4; ++k)
    gload_lds16(g_b + (size_t)k * 32 * M_ + srcoff,
                &gbase[(k * 256 + wslot) * 8]);
  __syncthreads();

  for (int it = 0; it < 8; ++it) {
    int cur = it & 1;
    const short* g_c = gbase + cur * 8192;
    // issue next tile's DMA staging + phi prefetch (overlaps this iter)
    int4 pnxt[4];
    if (it < 7) {
      int m0n = (it + 1) * 64;
#pragma unroll
      for (int k = 0; k < 4; ++k)
        gload_lds16(g_b + (size_t)k * 32 * M_ + srcoff + m0n,
                    &gbase[(cur ^ 1) * 8192 + (k * 256 + wslot) * 8]);
#pragma unroll
      for (int mt = 0; mt < 4; ++mt)
        pnxt[mt] = *(const int4*)&phi_b[(mbase + m0n + 16 * mt + q) * CK + 8 * h];
    }

    // QK^T from registers: P^T[m][n], own 16-n slice, own m-half
    f32x4 pt[4];
#pragma unroll
    for (int mt = 0; mt < 4; ++mt)
      pt[mt] = __builtin_amdgcn_mfma_f32_16x16x32_bf16(asbf(pcur[mt]), qfrag, zero4, 0, 0, 0);

    // static softmax numerator; P stays in registers (pk[])
    int2 pk[4];
#pragma unroll
    for (int mt = 0; mt < 4; ++mt) {
      float e0 = __expf(pt[mt][0]);
      float e1 = __expf(pt[mt][1]);
      float e2 = __expf(pt[mt][2]);
      float e3 = __expf(pt[mt][3]);
      S += (e0 + e1) + (e2 + e3);
      pk[mt].x = cvtpk(e0, e1);
      pk[mt].y = cvtpk(e2, e3);
    }

    // PV: O^T[all 128 c][own 16 n]; B = own pk regs; A = swizzled LDS read
    __builtin_amdgcn_s_setprio(1);
#pragma unroll
    for (int kp = 0; kp < 2; ++kp) {
      int4 pfi;
      pfi.x = pk[2 * kp].x;     pfi.y = pk[2 * kp].y;
      pfi.z = pk[2 * kp + 1].x; pfi.w = pk[2 * kp + 1].y;
      bf16x8 pf = asbf(pfi);
#pragma unroll
      for (int ct = 0; ct < 8; ++ct) {
        bf16x8 vf = *(const bf16x8*)&g_c[(16 * ct + q) * 64 +
                                         (((4 * kp + h) ^ (q & 7)) * 8)];
        Oacc[ct] = __builtin_amdgcn_mfma_f32_16x16x32_bf16(vf, pf, Oacc[ct], 0, 0, 0);
      }
    }
    __builtin_amdgcn_s_setprio(0);

    if (it < 7) {
#pragma unroll
      for (int mt = 0; mt < 4; ++mt) pcur[mt] = pnxt[mt];
    }
    __syncthreads();  // drains DMA (compiler vmcnt) + swaps buffers
  }

  // per-wave denominator reduce (each lane -> full half-sum for its n)
  S += __shfl_xor(S, 16);
  S += __shfl_xor(S, 32);

  // ---- half-merge through LDS (V region dead): O_unnorm and S just ADD
  float* otf = (float*)lds;        // [64 n][132 f32]
  float* s_f = otf + 64 * 132;     // 64 floats
  int row = 16 * w_n + q;
  if (w_m == 1) {
#pragma unroll
    for (int ct = 0; ct < 8; ++ct)
      *(f32x4*)&otf[row * 132 + 16 * ct + 4 * h] = Oacc[ct];
    if (h == 0) s_f[row] = S;
  }
  __syncthreads();
  if (w_m == 0) {
#pragma unroll
    for (int ct = 0; ct < 8; ++ct)
      Oacc[ct] += *(const f32x4*)&otf[row * 132 + 16 * ct + 4 * h];
    S += s_f[row];
  }
  float rS = 1.f / S;
  __syncthreads();  // otf reads done before ot_s overwrites the region

  // ---- epilogue: normalized O -> ot_s (w_m=0 waves); w_o in TWO 128-row
  // halves. Peak LDS 8704 + 16384 = 25088 sh = 50,176 B.
  short* ot_s = lds;            // 64 n x stride 136 = 8704 sh
  short* wo_s = lds + 8704;     // 128 o x 128 c = 16384 sh, swizzle g^(o&7)
  if (w_m == 0) {
#pragma unroll
    for (int ct = 0; ct < 8; ++ct) {
      int2 pp;
      pp.x = cvtpk(Oacc[ct][0] * rS, Oacc[ct][1] * rS);
      pp.y = cvtpk(Oacc[ct][2] * rS, Oacc[ct][3] * rS);
      *(int2*)&ot_s[row * 136 + 16 * ct + 4 * h] = pp;
    }
  }

  int jj = w & 3, np = w >> 2;  // wave: o-pair jj (32 o), n-half np (32 n)
#pragma unroll
  for (int ho = 0; ho < 2; ++ho) {
    // stage w_o rows [128*ho, 128*ho+128) from f32:
    // 128 rows x 128 c = 2048 int4 -> 512 threads x 4 reps (r20 bug: was 2)
#pragma unroll
    for (int rep = 0; rep < 4; ++rep) {
      int idx = rep * 512 + tid;
      int ol = idx >> 4, gp = idx & 15;
      const float* src = wo + (size_t)(128 * ho + ol) * 128 + gp * 8;
      float4 f0 = *(const float4*)src;
      float4 f1 = *(const float4*)(src + 4);
      int4 pk2;
      pk2.x = cvtpk(f0.x, f0.y); pk2.y = cvtpk(f0.z, f0.w);
      pk2.z = cvtpk(f1.x, f1.y); pk2.w = cvtpk(f1.z, f1.w);
      *(int4*)&wo_s[ol * 128 + ((gp ^ (ol & 7)) * 8)] = pk2;
    }
    __syncthreads();

    // wave (jj, np): o rows 32jj..32jj+31 (2 tiles), n cols 32np..32np+31
    f32x4 acc[2][2];
#pragma unroll
    for (int j = 0; j < 2; ++j)
#pragma unroll
      for (int i = 0; i < 2; ++i) acc[j][i] = (f32x4){0.f, 0.f, 0.f, 0.f};

#pragma unroll
    for (int ks = 0; ks < 4; ++ks) {
      bf16x8 bfr[2];
#pragma unroll
      for (int i = 0; i < 2; ++i)
        bfr[i] = *(const bf16x8*)&ot_s[(32 * np + 16 * i + q) * 136 + 32 * ks + 8 * h];
#pragma unroll
      for (int j = 0; j < 2; ++j) {
        int ol = 32 * jj + 16 * j + q;
        bf16x8 afr = *(const bf16x8*)&wo_s[ol * 128 + (((4 * ks + h) ^ (ol & 7)) * 8)];
#pragma unroll
        for (int i = 0; i < 2; ++i)
          acc[j][i] = __builtin_amdgcn_mfma_f32_16x16x32_bf16(afr, bfr[i], acc[j][i], 0, 0, 0);
      }
    }

#pragma unroll
    for (int j = 0; j < 2; ++j)
#pragma unroll
      for (int i = 0; i < 2; ++i)
#pragma unroll
        for (int r = 0; r < 4; ++r) {
          int o = 128 * ho + 32 * jj + 16 * j + 4 * h + r;
          int nn = n0 + 32 * np + 16 * i + q;
          size_t idx = ((size_t)b * C_ + o) * N_ + nn;
          out[idx] = gm * acc[j][i][r] + x[idx];
        }
    if (ho == 0) __syncthreads();  // wo_s reads done before restage
  }
}

extern "C" void kernel_launch(void* const* d_in, const int* in_sizes, int n_in,
                              void* d_out, int out_size, void* d_ws, size_t ws_size,
                              hipStream_t stream) {
  const float* x = (const float*)d_in[0];
  const float* wt = (const float*)d_in[1];
  const float* wp = (const float*)d_in[2];
  const float* wg = (const float*)d_in[3];
  const float* wo = (const float*)d_in[4];
  const float* gamma = (const float*)d_in[5];
  float* out = (float*)d_out;

  short* theta_t = (short*)d_ws;                       // 8*4096*32
  short* phi_t = theta_t + (size_t)B_ * N_ * CK;       // 8*1024*32
  short* g_bf = phi_t + (size_t)B_ * M_ * CK;          // 8*128*1024

  proj_kernel<<<dim3(64, 8), 512, 0, stream>>>(x, wt, wp, wg, theta_t, phi_t, g_bf);
  attn_out_kernel<<<dim3(512), 512, 0, stream>>>(theta_t, phi_t, g_bf, wo, x, gamma, out);
}